// Round 11
// baseline (613.472 us; speedup 1.0000x reference)
//
#include <hip/hip_runtime.h>
#include <hip/hip_cooperative_groups.h>

namespace cg = cooperative_groups;

// ---------------- problem constants ----------------
constexpr int Bb = 2;
constexpr int Ss = 256;
constexpr int Dd = 512;
constexpr int Vv = 32000;
constexpr int NVB = Vv / 64;          // 500 v-bands (partial rows)
constexpr float GAMMA_C = 2.0f;
constexpr int MEMLEN = 16;
constexpr int NMEM = 256;
constexpr int MTOT = (8 + 4) * MEMLEN;   // 192
constexpr int CTXROWS = MTOT + Ss;       // 448

// output layout (floats)
constexpr size_t NQ   = (size_t)Bb * Ss * Dd;        // 262144
constexpr size_t OC1  = NQ;                          // 262144
constexpr size_t NCTX = (size_t)Bb * CTXROWS * Dd;   // 458752
constexpr size_t OC2  = OC1 + NCTX;                  // 720896
constexpr size_t OMASK = OC2 + NCTX;                 // 1179648

constexpr size_t WS_FLOATS_NEEDED = 256000 + 512 + 512 + 131072 + 131584 + 512 +
                                    1024 + 1024 + 512 + 196608 + 196608 + 4096;

// ---------------- shared 64x64 fp32 GEMM core (K=512) — sims/mlp ----------
__device__ __forceinline__ void gemm64x64_k512(const float* __restrict__ A,
                                               const float* __restrict__ Bm,
                                               float acc[4][4],
                                               float4* __restrict__ Qs4,
                                               float4* __restrict__ Ws4) {
  const int t = threadIdx.x;
  const int tn = t & 15, tm = t >> 4;
  float* __restrict__ Qf = (float*)Qs4;
  float* __restrict__ Wf = (float*)Ws4;
  #pragma unroll 2
  for (int kc = 0; kc < 512; kc += 32) {
    #pragma unroll
    for (int e = 0; e < 2; ++e) {
      const int idx4 = t + 256 * e;        // 0..511
      const int m = idx4 >> 3;             // 0..63
      const int kg = idx4 & 7;             // k-group
      const float4 qa = *(const float4*)(A + (size_t)m * 512 + kc + kg * 4);
      const float4 wb = *(const float4*)(Bm + (size_t)m * 512 + kc + kg * 4);
      const int fb = ((kg * 4) * 16 + ((m >> 2) ^ kg)) * 4 + (m & 3);
      Qf[fb]       = qa.x; Qf[fb + 64]  = qa.y;
      Qf[fb + 128] = qa.z; Qf[fb + 192] = qa.w;
      Wf[fb]       = wb.x; Wf[fb + 64]  = wb.y;
      Wf[fb + 128] = wb.z; Wf[fb + 192] = wb.w;
    }
    __syncthreads();
    #pragma unroll
    for (int k = 0; k < 32; ++k) {
      const int swz = (k >> 2) & 7;
      const float4 a4 = Qs4[k * 16 + (tm ^ swz)];
      const float4 b4 = Ws4[k * 16 + (tn ^ swz)];
      const float av[4] = {a4.x, a4.y, a4.z, a4.w};
      const float bv[4] = {b4.x, b4.y, b4.z, b4.w};
      #pragma unroll
      for (int i = 0; i < 4; ++i)
        #pragma unroll
        for (int j = 0; j < 4; ++j)
          acc[i][j] += av[i] * bv[j];
    }
    __syncthreads();
  }
}

// ---------------- 1) logits: 128x128 tile (2 row-halves x 2 col-bands) ----------
// Per-output FMA chain k-ascending; per-(row,band) epilogue partition identical to
// the validated kernels -> partial[] BIT-EXACT.
__global__ __launch_bounds__(256) void k_logits(const float* __restrict__ q,
                                                const float* __restrict__ bw,
                                                float* __restrict__ partial) {
  __shared__ float4 As4[1024];   // 2 halves x 64 rows x 32 k (swizzled)
  __shared__ float4 Bs4[1024];   // 128 rows x 32 k (swizzled)
  __shared__ float red[64 * 17];
  const int bv = blockIdx.x;   // 0..249 (pair of 64-col bands)
  const int bm = blockIdx.y;   // 0..3  (128 rows)
  const int t = threadIdx.x;
  const int tn = t & 15, tm = t >> 4;
  const float* A  = q  + (size_t)bm * 128 * 512;
  const float* Bm = bw + (size_t)bv * 128 * 512;
  float* Af = (float*)As4;
  float* Bf = (float*)Bs4;
  float acc00[4][4] = {};   // half0 band0
  float acc01[4][4] = {};   // half0 band1
  float acc10[4][4] = {};   // half1 band0
  float acc11[4][4] = {};   // half1 band1
  #pragma unroll 1
  for (int kc = 0; kc < 512; kc += 32) {
    #pragma unroll
    for (int e = 0; e < 4; ++e) {        // stage A: 1024 float4
      const int idx = t + 256 * e;
      const int mf = idx >> 3, kg = idx & 7;
      const float4 v = *(const float4*)(A + (size_t)mf * 512 + kc + kg * 4);
      const int h = mf >> 6, m = mf & 63;
      const int fb = h * 2048 + ((kg * 4) * 16 + ((m >> 2) ^ kg)) * 4 + (m & 3);
      Af[fb] = v.x; Af[fb + 64] = v.y; Af[fb + 128] = v.z; Af[fb + 192] = v.w;
    }
    #pragma unroll
    for (int e = 0; e < 4; ++e) {        // stage B: 1024 float4
      const int idx = t + 256 * e;
      const int mB = idx >> 3, kg = idx & 7;
      const float4 v = *(const float4*)(Bm + (size_t)mB * 512 + kc + kg * 4);
      const int m4 = mB >> 2;
      const int g = (m4 & 24) | ((m4 & 7) ^ kg);
      const int fb = ((kg * 4) * 32 + g) * 4 + (mB & 3);
      Bf[fb] = v.x; Bf[fb + 128] = v.y; Bf[fb + 256] = v.z; Bf[fb + 384] = v.w;
    }
    __syncthreads();
    #pragma unroll
    for (int k = 0; k < 32; ++k) {
      const int swz = (k >> 2) & 7;
      const float4 alo = As4[k * 16 + (tm ^ swz)];
      const float4 ahi = As4[512 + k * 16 + (tm ^ swz)];
      const int g0 = (tn & 8) | ((tn & 7) ^ swz);
      const float4 b0 = Bs4[k * 32 + g0];
      const float4 b1 = Bs4[k * 32 + 16 + g0];
      const float al[4] = {alo.x, alo.y, alo.z, alo.w};
      const float ah[4] = {ahi.x, ahi.y, ahi.z, ahi.w};
      const float b0v[4] = {b0.x, b0.y, b0.z, b0.w};
      const float b1v[4] = {b1.x, b1.y, b1.z, b1.w};
      #pragma unroll
      for (int i = 0; i < 4; ++i)
        #pragma unroll
        for (int j = 0; j < 4; ++j) {
          acc00[i][j] += al[i] * b0v[j];
          acc01[i][j] += al[i] * b1v[j];
          acc10[i][j] += ah[i] * b0v[j];
          acc11[i][j] += ah[i] * b1v[j];
        }
    }
    __syncthreads();
  }
  // 4 epilogue passes (half, band) — identical per-(row,band) order as validated
  #pragma unroll
  for (int h = 0; h < 2; ++h) {
    #pragma unroll
    for (int band = 0; band < 2; ++band) {
      #pragma unroll
      for (int i = 0; i < 4; ++i) {
        float s = 0.f;
        #pragma unroll
        for (int j = 0; j < 4; ++j) {
          float v = (h == 0) ? ((band == 0) ? acc00[i][j] : acc01[i][j])
                             : ((band == 0) ? acc10[i][j] : acc11[i][j]);
          s += expf(v);
        }
        red[(tm * 4 + i) * 17 + tn] = s;
      }
      __syncthreads();
      if (t < 64) {
        float s = 0.f;
        #pragma unroll
        for (int j = 0; j < 16; ++j) s += red[t * 17 + j];
        partial[(size_t)(bv * 2 + band) * 512 + bm * 128 + h * 64 + t] = s;
      }
      __syncthreads();
    }
  }
}

// ---------------- 2) cooperative mega-kernel: everything else ----------------
struct CoopParams {
  const float* q;
  const float* key;
  const float* amask;
  const float* bw;
  const int*   tgt;
  const float* partial;
  const float* simw;
  const float* simb;
  const int*   meml;
  const float* memk;
  const float* memv;
  const float* w1;
  const float* b1;
  const float* w2;
  const float* b2;
  float* sims;
  float* qbar;
  double* pc;
  float* R;
  float* deg;
  float* sur;
  int* bnd;
  int* nseg;
  int* segst;
  int* segcnt;
  int* slotb;
  int* slotst;
  int* slotcnt;
  int* cont;
  int* topi;
  float* qm;
  float* scores;
  float* xg;
  float* h;
  float* out;
};

__global__ __launch_bounds__(256) void k_coop(CoopParams P) {
  cg::grid_group gg = cg::this_grid();
  __shared__ __align__(16) char smem[16640];
  const int b = blockIdx.x, t = threadIdx.x;
  const int wv = t >> 6, lane = t & 63;

  // ---- PA: sims(b<32) | qbar(32..35) | lse(36..51) | copy(52..127) ----
  if (b < 32) {
    float4* Qs4 = (float4*)smem;
    float4* Ws4 = Qs4 + 512;
    int bb = b >> 4, rem = b & 15;
    int m0 = (rem >> 2) * 64, n0 = (rem & 3) * 64;
    float acc[4][4] = {};
    const float* qb = P.q + (size_t)bb * Ss * Dd;
    gemm64x64_k512(qb + (size_t)m0 * 512, qb + (size_t)n0 * 512, acc, Qs4, Ws4);
    int tn = t & 15, tm = t >> 4;
    float* outp = P.sims + (size_t)bb * Ss * Ss;
    #pragma unroll
    for (int i = 0; i < 4; ++i) {
      float4 v = make_float4(acc[i][0], acc[i][1], acc[i][2], acc[i][3]);
      *(float4*)&outp[(size_t)(m0 + tm * 4 + i) * 256 + n0 + tn * 4] = v;
    }
  } else if (b < 36) {
    int id = (b - 32) * 256 + t;   // 0..1023
    int bb = id >> 9, d = id & 511;
    float s = 0.f;
    for (int ss2 = 0; ss2 < 256; ++ss2) s += P.q[((size_t)(bb * 256 + ss2)) * 512 + d];
    P.qbar[id] = s * (1.0f / 256.0f);
  } else if (b < 52) {
    int idx = b - 36;   // 0..15
    int c = idx >> 1, rb = idx & 1;
    int r = rb * 256 + t;
    int j0 = c * 63, j1 = (j0 + 63 < NVB) ? j0 + 63 : NVB;
    double s = 0.0;
    for (int j = j0; j < j1; ++j) s += (double)P.partial[(size_t)j * 512 + r];
    P.pc[c * 512 + r] = s;
  } else {
    for (int ci = b - 52; ci < 2052; ci += 76) {   // 2052 = 76*27 exact
      int id = ci * 256 + t;
      if (id < 262144) {
        P.out[id] = P.q[id];
      } else if (id < 524288) {
        int id2 = id - 262144;
        int bb = id2 >> 17;
        int s = (id2 >> 9) & 255;
        int d = id2 & 511;
        float v = P.key[id2];
        size_t p = OC1 + ((size_t)(bb * 448 + 192 + s)) * 512 + d;
        P.out[p] = v;
        P.out[p + NCTX] = v;
      } else if (id < 525184) {
        int j = id - 524288;   // 0..895
        int bb = j / 448, c = j - bb * 448;
        P.out[OMASK + j] = (c < 192) ? 1.0f : P.amask[bb * 256 + (c - 192)];
      }
    }
  }
  gg.sync();

  // ---- PB: sur | rowpref | qm (independent) ----
  {
    int wid = b * 4 + wv;            // 0..511
    // sur
    {
      int tg = P.tgt[wid];
      const float* qp = P.q + (size_t)wid * 512;
      const float* wp = P.bw + (size_t)tg * 512;
      float a = 0.f;
      #pragma unroll
      for (int j = 0; j < 8; ++j) a += qp[lane + 64 * j] * wp[lane + 64 * j];
      #pragma unroll
      for (int off = 32; off; off >>= 1) a += __shfl_xor(a, off);
      if (lane == 0) {
        double s = 0.0;
        #pragma unroll
        for (int c = 0; c < 8; ++c) s += P.pc[c * 512 + wid];
        P.sur[wid] = (float)log(s) - a;
      }
    }
    // rowpref
    {
      int bb = wid >> 8, i = wid & 255;
      const float* row = P.sims + (size_t)bb * 65536 + (size_t)i * 256;
      float4 v = *(const float4*)&row[lane * 4];
      float c0 = v.x, c1 = c0 + v.y, c2 = c1 + v.z, c3 = c2 + v.w;
      float ls = c3;
      float sc = ls;
      for (int off = 1; off < 64; off <<= 1) {
        float u = __shfl_up(sc, off);
        if (lane >= off) sc += u;
      }
      float ex = sc - ls;
      float* Rr = P.R + (size_t)bb * (256 * 257) + (size_t)i * 257;
      Rr[lane * 4 + 1] = ex + c0;
      Rr[lane * 4 + 2] = ex + c1;
      Rr[lane * 4 + 3] = ex + c2;
      Rr[lane * 4 + 4] = ex + c3;
      if (lane == 0) Rr[0] = 0.f;
      if (lane == 63) P.deg[bb * 256 + i] = ex + c3;
    }
    // qm (1024 rows over 512 waves: 2 halves)
    #pragma unroll
    for (int half = 0; half < 2; ++half) {
      int wid2 = half * 512 + wid;
      int bb = wid2 >> 9, e = wid2 & 511;
      float a = 0.f;
      #pragma unroll
      for (int j = 0; j < 8; ++j)
        a += P.qbar[bb * 512 + lane + 64 * j] * P.simw[(size_t)e * 512 + lane + 64 * j];
      #pragma unroll
      for (int off = 32; off; off >>= 1) a += __shfl_xor(a, off);
      if (lane == 0) P.qm[bb * 512 + e] = a + P.simb[e];
    }
  }
  gg.sync();

  // ---- PC: bound (blocks 0,1) ----
  if (b < 2) {
    float* ss = (float*)smem;        // 256
    float* thrw = ss + 256;          // 237
    ss[t] = P.sur[b * 256 + t];
    __syncthreads();
    if (t < 237) {
      float mn = 0.f;
      #pragma unroll
      for (int e = 0; e < 20; ++e) mn += ss[t + e];
      mn *= (1.0f / 20.0f);
      float v = 0.f;
      #pragma unroll
      for (int e = 0; e < 20; ++e) { float d = ss[t + e] - mn; v += d * d; }
      thrw[t] = mn + GAMMA_C * sqrtf(v * (1.0f / 19.0f));   // ddof=1
    }
    __syncthreads();
    float th = (t <= 18) ? thrw[0] : thrw[t - 19];
    P.bnd[b * 256 + t] = (ss[t] > th) ? 1 : 0;
  }
  gg.sync();

  // ---- PD: refine (blocks 0,1) — bit-identical aggregation order ----
  if (b < 2) {
    int* sb    = (int*)smem;              // 256
    int* lab   = sb + 256;                // 256
    int* segst = lab + 256;               // 258
    float* Dc    = (float*)(segst + 258); // 257
    float* Sc    = Dc + 257;              // 257
    float* Cr    = Sc + 257;              // 257
    float* degsh = Cr + 257;              // 256
    float* Stm   = degsh + 256;           // 256
    float* Ctm   = Stm + 256;             // 256
    float* sh    = Ctm + 256;             // 6
    sb[t] = P.bnd[b * 256 + t];
    degsh[t] = P.deg[b * 256 + t];
    for (int c = t; c < 258; c += 256) segst[c] = -1;
    __syncthreads();
    int a = 0;
    for (int i = 0; i <= t; ++i) a += sb[i];
    lab[t] = a;
    __syncthreads();
    if (t == 0 || lab[t - 1] != lab[t]) segst[lab[t]] = t;
    __syncthreads();
    int nb = lab[255];
    const float* Rb = P.R + (size_t)b * (256 * 257);
    {
      int c = lab[t];
      int a1 = segst[c];
      int e1 = (c == nb) ? 255 : (segst[c + 1] - 1);
      const float* Rrow = Rb + (size_t)t * 257;
      Stm[t] = Rrow[e1 + 1] - Rrow[a1];
      float cv = 0.f;
      if (c < nb) {
        int a2 = segst[c + 1];
        int e2 = (c + 1 == nb) ? 255 : (segst[c + 2] - 1);
        cv = Rrow[e2 + 1] - Rrow[a2];
      }
      Ctm[t] = cv;
    }
    __syncthreads();
    for (int c = t; c <= nb; c += 256) {
      float Dv = 0.f, Sv = 0.f, Cv = 0.f;
      int a1 = segst[c];
      if (a1 >= 0) {
        int e1 = (c == nb) ? 255 : (segst[c + 1] - 1);
        for (int i = a1; i <= e1; ++i) { Dv += degsh[i]; Sv += Stm[i]; Cv += Ctm[i]; }
      }
      Dc[c] = Dv; Sc[c] = Sv; Cr[c] = Cv;
    }
    __syncthreads();
    if (t == 0) {
      float tot = 0.f;
      for (int i = 0; i < 256; ++i) tot += degsh[i];
      float tote = tot + 1e-10f;
      float Qun = 0.f, Cs = 0.f;
      for (int c = 0; c <= nb; ++c) {
        Qun += Sc[c] - Dc[c] * Dc[c] / tote;
        Cs  += (Dc[c] - Sc[c]) / (fminf(Dc[c], tot - Dc[c]) + 1e-10f);
      }
      sh[0] = tot; sh[1] = tote; sh[2] = Qun; sh[3] = Cs;
      sh[4] = Qun / tote; sh[5] = Cs / (float)(nb + 1);
    }
    __syncthreads();
    int r = sb[t];
    if (r == 1) {
      float tot = sh[0], tote = sh[1], Qun = sh[2], Cs = sh[3], curQ = sh[4], curC = sh[5];
      int c2 = lab[t], c1 = c2 - 1;
      if (segst[c1] < 0) {
        float newC0 = Cs / (float)nb;
        if (newC0 < curC) r = 0;
      } else {
        float D1 = Dc[c1], S1 = Sc[c1], D2 = Dc[c2], S2 = Sc[c2];
        float Dm = D1 + D2, Sm = S1 + S2 + 2.0f * Cr[c1];
        float tq1 = S1 - D1 * D1 / tote;
        float tq2 = S2 - D2 * D2 / tote;
        float tqm = Sm - Dm * Dm / tote;
        float newQ = (Qun - tq1 - tq2 + tqm) / tote;
        float tc1 = (D1 - S1) / (fminf(D1, tot - D1) + 1e-10f);
        float tc2 = (D2 - S2) / (fminf(D2, tot - D2) + 1e-10f);
        float tcm = (Dm - Sm) / (fminf(Dm, tot - Dm) + 1e-10f);
        float newC = (Cs - tc1 - tc2 + tcm) / (float)nb;
        if (newQ > curQ || newC < curC) r = 0;
      }
    }
    __syncthreads();
    sb[t] = r;
    __syncthreads();
    if (t == 0) {
      int ns = 0, st = 0;
      for (int i = 1; i <= 256; ++i) {
        if (i == 256 || sb[i] == 1) {
          P.segst[b * 257 + ns] = st;
          P.segcnt[b * 257 + ns] = i - st;
          ns++;
          st = i;
        }
      }
      P.nseg[b] = ns;
    }
  }
  gg.sync();

  // ---- PE: slots (block 0) ----
  if (b == 0) {
    unsigned char* validsh = (unsigned char*)smem;   // 256
    int* ns01 = (int*)(smem + 256);                  // 2
    if (t < 2) ns01[t] = P.nseg[t];
    __syncthreads();
    int ns0 = ns01[0], total = ns0 + ns01[1];
    int rank = -1;
    for (int r = t; r < total; r += 256) rank = r;
    int bb = 0, st = 0, ct = 0;
    if (rank >= 0) {
      bb = (rank >= ns0) ? 1 : 0;
      int s = rank - bb * ns0;
      st = P.segst[bb * 257 + s];
      ct = P.segcnt[bb * 257 + s];
    }
    P.slotb[t] = bb; P.slotst[t] = st; P.slotcnt[t] = ct;
    validsh[t] = (ct > 0 || P.meml[t] > 0) ? 1 : 0;
    __syncthreads();
    if (t == 0) {
      int k = 0;
      for (int n = 255; n >= 0 && k < 4; --n) if (validsh[n]) P.cont[k++] = n;
      for (int n = 0; n < 256 && k < 4; ++n) if (!validsh[n]) P.cont[k++] = n;
    }
  }
  gg.sync();

  // ---- PF: scores (all blocks) ----
  {
    int wid = b * 4 + wv;   // 0..511
    int bb = wid >> 8, n = wid & 255;
    const float* kp = nullptr;
    if (P.slotcnt[n] > 0) kp = P.q + ((size_t)(P.slotb[n] * 256 + P.slotst[n])) * 512;
    else if (P.meml[n] > 0) kp = P.memk + (size_t)n * 512;
    float a = 0.f;
    if (kp) {
      #pragma unroll
      for (int j = 0; j < 8; ++j) a += P.qm[bb * 512 + lane + 64 * j] * kp[lane + 64 * j];
      #pragma unroll
      for (int off = 32; off; off >>= 1) a += __shfl_xor(a, off);
    }
    if (lane == 0) P.scores[bb * 256 + n] = kp ? a : -1000000000.0f;
  }
  gg.sync();

  // ---- PG: top-8 (blocks 0,1; wave 0) ----
  if (b < 2 && t < 64) {
    float v[4];
    #pragma unroll
    for (int j = 0; j < 4; ++j) v[j] = P.scores[b * 256 + t * 4 + j];
    int chosen = 0;
    for (int k = 0; k < 8; ++k) {
      float best = -3.4e38f; int bi = 0x7fffffff;
      #pragma unroll
      for (int j = 0; j < 4; ++j) {
        if (!(chosen & (1 << j))) {
          float s = v[j]; int n = t * 4 + j;
          if (s > best || (s == best && n < bi)) { best = s; bi = n; }
        }
      }
      #pragma unroll
      for (int off = 32; off; off >>= 1) {
        float ob = __shfl_xor(best, off);
        int oi = __shfl_xor(bi, off);
        if (ob > best || (ob == best && oi < bi)) { best = ob; bi = oi; }
      }
      if ((bi >> 2) == t) chosen |= 1 << (bi & 3);
      if (t == 0) P.topi[b * 8 + k] = bi;
    }
  }
  gg.sync();

  // ---- PH: gather (grid-stride, 768 chunk-blocks over 128) ----
  for (int gi = b; gi < 768; gi += 128) {
    int id = gi * 256 + t;   // < 196608
    int d = id & 511;
    int rb = id >> 9;        // 0..383
    int bb = rb / 192;
    int r = rb - bb * 192;
    int p = r & 15;
    int slot = (r < 128) ? P.topi[bb * 8 + (r >> 4)] : P.cont[(r - 128) >> 4];
    float val;
    int cnt = P.slotcnt[slot];
    if (cnt > 0) {
      int ml = cnt < 16 ? cnt : 16;
      val = (p < ml) ? P.q[((size_t)(P.slotb[slot] * 256 + P.slotst[slot] + p)) * 512 + d] : 0.f;
    } else {
      val = P.memv[((size_t)slot * 16 + p) * 512 + d];
    }
    P.xg[id] = val;
  }
  gg.sync();

  // ---- PI: mlp1 (blocks 0..47) ----
  if (b < 48) {
    float4* Qs4 = (float4*)smem;
    float4* Ws4 = Qs4 + 512;
    int n0 = (b & 7) * 64, m0 = (b >> 3) * 64;
    float acc[4][4] = {};
    gemm64x64_k512(P.xg + (size_t)m0 * 512, P.w1 + (size_t)n0 * 512, acc, Qs4, Ws4);
    int tn = t & 15, tm = t >> 4;
    #pragma unroll
    for (int i = 0; i < 4; ++i) {
      int m = m0 + tm * 4 + i;
      #pragma unroll
      for (int j = 0; j < 4; ++j) {
        int n = n0 + tn * 4 + j;
        P.h[(size_t)m * 512 + n] = fmaxf(acc[i][j] + P.b1[n], 0.f);
      }
    }
  }
  gg.sync();

  // ---- PJ: mlp2 (blocks 0..47) ----
  if (b < 48) {
    float4* Qs4 = (float4*)smem;
    float4* Ws4 = Qs4 + 512;
    int n0 = (b & 7) * 64, m0 = (b >> 3) * 64;
    float acc[4][4] = {};
    gemm64x64_k512(P.h + (size_t)m0 * 512, P.w2 + (size_t)n0 * 512, acc, Qs4, Ws4);
    int tn = t & 15, tm = t >> 4;
    #pragma unroll
    for (int i = 0; i < 4; ++i) {
      int m = m0 + tm * 4 + i;
      int bb = (m >= 192) ? 1 : 0;
      int rr = m - bb * 192;
      int n = n0 + tn * 4;
      float4 v = make_float4(acc[i][0] + P.b2[n], acc[i][1] + P.b2[n + 1],
                             acc[i][2] + P.b2[n + 2], acc[i][3] + P.b2[n + 3]);
      size_t base = OC1 + ((size_t)(bb * 448 + rr)) * 512 + n;
      *(float4*)&P.out[base] = v;
      *(float4*)&P.out[base + NCTX] = v;
    }
  }
}

// ---------------- launch ----------------
extern "C" void kernel_launch(void* const* d_in, const int* in_sizes, int n_in,
                              void* d_out, int out_size, void* d_ws, size_t ws_size,
                              hipStream_t stream) {
  if (ws_size < WS_FLOATS_NEEDED * sizeof(float)) return;

  const float* q     = (const float*)d_in[0];
  const float* key   = (const float*)d_in[1];
  const float* amask = (const float*)d_in[3];
  const int*   tgt   = (const int*)d_in[4];
  const float* bw    = (const float*)d_in[5];
  const float* w1    = (const float*)d_in[6];
  const float* b1    = (const float*)d_in[7];
  const float* w2    = (const float*)d_in[8];
  const float* b2    = (const float*)d_in[9];
  const float* simw  = (const float*)d_in[10];
  const float* simb  = (const float*)d_in[11];
  const float* memk  = (const float*)d_in[12];
  const float* memv  = (const float*)d_in[13];
  const int*   meml  = (const int*)d_in[14];
  float* out = (float*)d_out;

  float* w = (float*)d_ws;
  float* p_partial = w;                      // 256000
  float* p_lse    = p_partial + 256000;      // 512 (unused)
  float* p_sur    = p_lse + 512;             // 512
  float* p_sims   = p_sur + 512;             // 131072
  float* p_R      = p_sims + 131072;         // 131584
  float* p_deg    = p_R + 131584;            // 512
  float* p_qbar   = p_deg + 512;             // 1024
  float* p_qm     = p_qbar + 1024;           // 1024
  float* p_scores = p_qm + 1024;             // 512
  float* p_xg     = p_scores + 512;          // 196608
  float* p_h      = p_xg + 196608;           // 196608
  double* p_pc    = (double*)p_h;            // 8*512 doubles; consumed (PB) before h written (PI)
  int* ip         = (int*)(p_h + 196608);
  int* ip_bnd     = ip;                      // 512
  int* ip_nseg    = ip + 512;                // 2
  int* ip_segst   = ip + 514;                // 514
  int* ip_segcnt  = ip + 1028;               // 514
  int* ip_slotb   = ip + 1542;               // 256
  int* ip_slotst  = ip + 1798;               // 256
  int* ip_slotcnt = ip + 2054;               // 256
  int* ip_topi    = ip + 2310;               // 16
  int* ip_cont    = ip + 2326;               // 4

  k_logits<<<dim3(250, 4), 256, 0, stream>>>(q, bw, p_partial);

  CoopParams P;
  P.q = q; P.key = key; P.amask = amask; P.bw = bw; P.tgt = tgt;
  P.partial = p_partial; P.simw = simw; P.simb = simb;
  P.meml = meml; P.memk = memk; P.memv = memv;
  P.w1 = w1; P.b1 = b1; P.w2 = w2; P.b2 = b2;
  P.sims = p_sims; P.qbar = p_qbar; P.pc = p_pc;
  P.R = p_R; P.deg = p_deg; P.sur = p_sur;
  P.bnd = ip_bnd; P.nseg = ip_nseg; P.segst = ip_segst; P.segcnt = ip_segcnt;
  P.slotb = ip_slotb; P.slotst = ip_slotst; P.slotcnt = ip_slotcnt;
  P.cont = ip_cont; P.topi = ip_topi;
  P.qm = p_qm; P.scores = p_scores; P.xg = p_xg; P.h = p_h; P.out = out;

  void* kargs[] = {(void*)&P};
  hipLaunchCooperativeKernel((const void*)k_coop, dim3(128), dim3(256), kargs, 0, stream);
}

// Round 13
// 453.805 us; speedup vs baseline: 1.3518x; 1.3518x over previous
//
#include <hip/hip_runtime.h>

// ---------------- problem constants ----------------
constexpr int Bb = 2;
constexpr int Ss = 256;
constexpr int Dd = 512;
constexpr int Vv = 32000;
constexpr int NVB = Vv / 64;          // 500 v-bands (partial rows)
constexpr float GAMMA_C = 2.0f;
constexpr int MEMLEN = 16;
constexpr int NMEM = 256;
constexpr int MTOT = (8 + 4) * MEMLEN;   // 192
constexpr int CTXROWS = MTOT + Ss;       // 448

// output layout (floats)
constexpr size_t NQ   = (size_t)Bb * Ss * Dd;        // 262144
constexpr size_t OC1  = NQ;                          // 262144
constexpr size_t NCTX = (size_t)Bb * CTXROWS * Dd;   // 458752
constexpr size_t OC2  = OC1 + NCTX;                  // 720896
constexpr size_t OMASK = OC2 + NCTX;                 // 1179648

constexpr size_t WS_FLOATS_NEEDED = 256000 + 512 + 512 + 131072 + 131584 + 512 +
                                    1024 + 1024 + 512 + 196608 + 196608 + 4096;

// K1 block ranges
constexpr int K1_LOGITS = 2000;            // 250 bv-pairs x 8 bm
constexpr int K1_SIMS   = K1_LOGITS + 32;  // 2032
constexpr int K1_QBAR   = K1_SIMS + 4;     // 2036
constexpr int K1_NBLK   = K1_QBAR + 2052;  // 4088

// ---------------- shared 64x64 fp32 GEMM core (K=512) ----------
__device__ __forceinline__ void gemm64x64_k512(const float* __restrict__ A,
                                               const float* __restrict__ Bm,
                                               float acc[4][4],
                                               float4* __restrict__ Qs4,
                                               float4* __restrict__ Ws4) {
  const int t = threadIdx.x;
  const int tn = t & 15, tm = t >> 4;
  float* __restrict__ Qf = (float*)Qs4;
  float* __restrict__ Wf = (float*)Ws4;
  #pragma unroll 2
  for (int kc = 0; kc < 512; kc += 32) {
    #pragma unroll
    for (int e = 0; e < 2; ++e) {
      const int idx4 = t + 256 * e;        // 0..511
      const int m = idx4 >> 3;             // 0..63
      const int kg = idx4 & 7;             // k-group
      const float4 qa = *(const float4*)(A + (size_t)m * 512 + kc + kg * 4);
      const float4 wb = *(const float4*)(Bm + (size_t)m * 512 + kc + kg * 4);
      const int fb = ((kg * 4) * 16 + ((m >> 2) ^ kg)) * 4 + (m & 3);
      Qf[fb]       = qa.x; Qf[fb + 64]  = qa.y;
      Qf[fb + 128] = qa.z; Qf[fb + 192] = qa.w;
      Wf[fb]       = wb.x; Wf[fb + 64]  = wb.y;
      Wf[fb + 128] = wb.z; Wf[fb + 192] = wb.w;
    }
    __syncthreads();
    #pragma unroll
    for (int k = 0; k < 32; ++k) {
      const int swz = (k >> 2) & 7;
      const float4 a4 = Qs4[k * 16 + (tm ^ swz)];
      const float4 b4 = Ws4[k * 16 + (tn ^ swz)];
      const float av[4] = {a4.x, a4.y, a4.z, a4.w};
      const float bv[4] = {b4.x, b4.y, b4.z, b4.w};
      #pragma unroll
      for (int i = 0; i < 4; ++i)
        #pragma unroll
        for (int j = 0; j < 4; ++j)
          acc[i][j] += av[i] * bv[j];
    }
    __syncthreads();
  }
}

// ---------------- K1: logits (R8-validated 64x128) + sims + qbar + copy ----------
__global__ __launch_bounds__(256) void k_main(const float* __restrict__ q,
                                              const float* __restrict__ bw,
                                              const float* __restrict__ key,
                                              const float* __restrict__ amask,
                                              float* __restrict__ partial,
                                              float* __restrict__ sims,
                                              float* __restrict__ qbar,
                                              float* __restrict__ out) {
  __shared__ __align__(16) char smem[28928];
  const int b = blockIdx.x, t = threadIdx.x;
  if (b < K1_LOGITS) {
    // ---- logits 64x128 (verbatim R8, bit-exact partial[]) ----
    float4* As4 = (float4*)smem;          // 512
    float4* Bs4 = As4 + 512;              // 1024
    float* red  = (float*)(Bs4 + 1024);   // 64*17
    const int bv = b >> 3;   // 0..249
    const int bm = b & 7;    // 0..7
    const int tn = t & 15, tm = t >> 4;
    const float* A  = q  + (size_t)bm * 64 * 512;
    const float* Bm = bw + (size_t)bv * 128 * 512;
    float* Af = (float*)As4;
    float* Bf = (float*)Bs4;
    float acc0[4][4] = {};
    float acc1[4][4] = {};
    #pragma unroll 1
    for (int kc = 0; kc < 512; kc += 32) {
      #pragma unroll
      for (int e = 0; e < 2; ++e) {        // stage A: 512 float4
        const int idx = t + 256 * e;
        const int m = idx >> 3, kg = idx & 7;
        const float4 v = *(const float4*)(A + (size_t)m * 512 + kc + kg * 4);
        const int fb = ((kg * 4) * 16 + ((m >> 2) ^ kg)) * 4 + (m & 3);
        Af[fb] = v.x; Af[fb + 64] = v.y; Af[fb + 128] = v.z; Af[fb + 192] = v.w;
      }
      #pragma unroll
      for (int e = 0; e < 4; ++e) {        // stage B: 1024 float4
        const int idx = t + 256 * e;
        const int mB = idx >> 3, kg = idx & 7;
        const float4 v = *(const float4*)(Bm + (size_t)mB * 512 + kc + kg * 4);
        const int m4 = mB >> 2;
        const int g = (m4 & 24) | ((m4 & 7) ^ kg);
        const int fb = ((kg * 4) * 32 + g) * 4 + (mB & 3);
        Bf[fb] = v.x; Bf[fb + 128] = v.y; Bf[fb + 256] = v.z; Bf[fb + 384] = v.w;
      }
      __syncthreads();
      #pragma unroll
      for (int k = 0; k < 32; ++k) {
        const int swz = (k >> 2) & 7;
        const float4 a4 = As4[k * 16 + (tm ^ swz)];
        const int g0 = (tn & 8) | ((tn & 7) ^ swz);
        const float4 b0 = Bs4[k * 32 + g0];
        const float4 b1 = Bs4[k * 32 + 16 + g0];
        const float av[4]  = {a4.x, a4.y, a4.z, a4.w};
        const float b0v[4] = {b0.x, b0.y, b0.z, b0.w};
        const float b1v[4] = {b1.x, b1.y, b1.z, b1.w};
        #pragma unroll
        for (int i = 0; i < 4; ++i)
          #pragma unroll
          for (int j = 0; j < 4; ++j) {
            acc0[i][j] += av[i] * b0v[j];
            acc1[i][j] += av[i] * b1v[j];
          }
      }
      __syncthreads();
    }
    #pragma unroll
    for (int i = 0; i < 4; ++i) {
      float s = 0.f;
      #pragma unroll
      for (int j = 0; j < 4; ++j) s += expf(acc0[i][j]);
      red[(tm * 4 + i) * 17 + tn] = s;
    }
    __syncthreads();
    if (t < 64) {
      float s = 0.f;
      #pragma unroll
      for (int j = 0; j < 16; ++j) s += red[t * 17 + j];
      partial[(size_t)(bv * 2) * 512 + bm * 64 + t] = s;
    }
    __syncthreads();
    #pragma unroll
    for (int i = 0; i < 4; ++i) {
      float s = 0.f;
      #pragma unroll
      for (int j = 0; j < 4; ++j) s += expf(acc1[i][j]);
      red[(tm * 4 + i) * 17 + tn] = s;
    }
    __syncthreads();
    if (t < 64) {
      float s = 0.f;
      #pragma unroll
      for (int j = 0; j < 16; ++j) s += red[t * 17 + j];
      partial[(size_t)(bv * 2 + 1) * 512 + bm * 64 + t] = s;
    }
  } else if (b < K1_SIMS) {
    // ---- sims = q q^T (64x64 tiles) ----
    float4* Qs4 = (float4*)smem;
    float4* Ws4 = Qs4 + 512;
    int bi2 = b - K1_LOGITS;
    int bb = bi2 >> 4, rem = bi2 & 15;
    int m0 = (rem >> 2) * 64, n0 = (rem & 3) * 64;
    float acc[4][4] = {};
    const float* qb = q + (size_t)bb * Ss * Dd;
    gemm64x64_k512(qb + (size_t)m0 * 512, qb + (size_t)n0 * 512, acc, Qs4, Ws4);
    int tn = t & 15, tm = t >> 4;
    float* outp = sims + (size_t)bb * Ss * Ss;
    #pragma unroll
    for (int i = 0; i < 4; ++i) {
      float4 v = make_float4(acc[i][0], acc[i][1], acc[i][2], acc[i][3]);
      *(float4*)&outp[(size_t)(m0 + tm * 4 + i) * 256 + n0 + tn * 4] = v;
    }
  } else if (b < K1_QBAR) {
    int id = (b - K1_SIMS) * 256 + t;   // 0..1023
    int bb = id >> 9, d = id & 511;
    float s = 0.f;
    for (int ss2 = 0; ss2 < 256; ++ss2) s += q[((size_t)(bb * 256 + ss2)) * 512 + d];
    qbar[id] = s * (1.0f / 256.0f);
  } else {
    int id = (b - K1_QBAR) * 256 + t;
    if (id < 262144) { out[id] = q[id]; return; }
    if (id < 524288) {
      int id2 = id - 262144;
      int bb = id2 >> 17;
      int s = (id2 >> 9) & 255;
      int d = id2 & 511;
      float v = key[id2];
      size_t p = OC1 + ((size_t)(bb * 448 + 192 + s)) * 512 + d;
      out[p] = v;
      out[p + NCTX] = v;
      return;
    }
    if (id < 525184) {
      int j = id - 524288;   // 0..895
      int bb = j / 448, c = j - bb * 448;
      out[OMASK + j] = (c < 192) ? 1.0f : amask[bb * 256 + (c - 192)];
    }
  }
}

// ---------------- K2: pc-chunks + rowpref + qm ----------------
__global__ __launch_bounds__(256) void k_mid(const float* __restrict__ partial,
                                             const float* __restrict__ sims,
                                             const float* __restrict__ qbar,
                                             const float* __restrict__ simw,
                                             const float* __restrict__ simb,
                                             double* __restrict__ pc,
                                             float* __restrict__ R,
                                             float* __restrict__ deg,
                                             float* __restrict__ qm) {
  const int b = blockIdx.x, t = threadIdx.x;
  const int wv = t >> 6, lane = t & 63;
  if (b < 16) {
    int c = b >> 1, rb2 = b & 1;
    int r = rb2 * 256 + t;
    int j0 = c * 63, j1 = (j0 + 63 < NVB) ? j0 + 63 : NVB;
    double s = 0.0;
    for (int j = j0; j < j1; ++j) s += (double)partial[(size_t)j * 512 + r];
    pc[c * 512 + r] = s;
  } else if (b < 144) {
    int wid = (b - 16) * 4 + wv;   // 0..511
    int bb = wid >> 8, i = wid & 255;
    const float* row = sims + (size_t)bb * 65536 + (size_t)i * 256;
    float4 v = *(const float4*)&row[lane * 4];
    float c0 = v.x, c1 = c0 + v.y, c2 = c1 + v.z, c3 = c2 + v.w;
    float ls = c3;
    float sc = ls;
    for (int off = 1; off < 64; off <<= 1) {
      float u = __shfl_up(sc, off);
      if (lane >= off) sc += u;
    }
    float ex = sc - ls;
    float* Rr = R + (size_t)bb * (256 * 257) + (size_t)i * 257;
    Rr[lane * 4 + 1] = ex + c0;
    Rr[lane * 4 + 2] = ex + c1;
    Rr[lane * 4 + 3] = ex + c2;
    Rr[lane * 4 + 4] = ex + c3;
    if (lane == 0) Rr[0] = 0.f;
    if (lane == 63) deg[bb * 256 + i] = ex + c3;
  } else {
    int wid2 = (b - 144) * 4 + wv;  // 0..1023
    int bb = wid2 >> 9, e = wid2 & 511;
    float a = 0.f;
    #pragma unroll
    for (int j = 0; j < 8; ++j)
      a += qbar[bb * 512 + lane + 64 * j] * simw[(size_t)e * 512 + lane + 64 * j];
    #pragma unroll
    for (int off = 32; off; off >>= 1) a += __shfl_xor(a, off);
    if (lane == 0) qm[bb * 512 + e] = a + simb[e];
  }
}

// ---------------- K3: sur ----------------
__global__ __launch_bounds__(256) void k_sur(const float* __restrict__ q,
                                             const float* __restrict__ bw,
                                             const int* __restrict__ tgt,
                                             const double* __restrict__ pc,
                                             float* __restrict__ sur) {
  int wid = blockIdx.x * 4 + (threadIdx.x >> 6);  // 0..511
  int lane = threadIdx.x & 63;
  int tg = tgt[wid];
  const float* qp = q + (size_t)wid * 512;
  const float* wp = bw + (size_t)tg * 512;
  float a = 0.f;
  #pragma unroll
  for (int j = 0; j < 8; ++j) a += qp[lane + 64 * j] * wp[lane + 64 * j];
  #pragma unroll
  for (int off = 32; off; off >>= 1) a += __shfl_xor(a, off);
  if (lane == 0) {
    double s = 0.0;
    #pragma unroll
    for (int c = 0; c < 8; ++c) s += pc[c * 512 + wid];
    sur[wid] = (float)log(s) - a;
  }
}

// ---------------- K4: bound + refine + slots + cont (ONE block, 512 thr) ----------
__global__ __launch_bounds__(512) void k_bndref(const float* __restrict__ sur,
                                                const float* __restrict__ R,
                                                const float* __restrict__ deg,
                                                const int* __restrict__ meml,
                                                int* __restrict__ nseg_g,
                                                int* __restrict__ segst_g,
                                                int* __restrict__ segcnt_g,
                                                int* __restrict__ slotb_g,
                                                int* __restrict__ slotst_g,
                                                int* __restrict__ slotcnt_g,
                                                int* __restrict__ cont_g) {
  __shared__ float ss[2][256], thrw[2][237];
  __shared__ int sb[2][256], lab[2][256], segst[2][258];
  __shared__ float Dc[2][257], Scs[2][257], Cr[2][257];
  __shared__ float degsh[2][256], Stm[2][256], Ctm[2][256];
  __shared__ float shv[2][6];
  __shared__ int segstL[2][257], segcntL[2][257], nsL[2];
  __shared__ unsigned char validsh[256];
  const int t = threadIdx.x;
  const int bt = t >> 8, tt = t & 255;
  // ---- bound ----
  ss[bt][tt] = sur[bt * 256 + tt];
  degsh[bt][tt] = deg[bt * 256 + tt];
  for (int c = tt; c < 258; c += 256) segst[bt][c] = -1;
  __syncthreads();
  if (tt < 237) {
    float mn = 0.f;
    #pragma unroll
    for (int e = 0; e < 20; ++e) mn += ss[bt][tt + e];
    mn *= (1.0f / 20.0f);
    float v = 0.f;
    #pragma unroll
    for (int e = 0; e < 20; ++e) { float d = ss[bt][tt + e] - mn; v += d * d; }
    thrw[bt][tt] = mn + GAMMA_C * sqrtf(v * (1.0f / 19.0f));   // ddof=1
  }
  __syncthreads();
  {
    float th = (tt <= 18) ? thrw[bt][0] : thrw[bt][tt - 19];
    sb[bt][tt] = (ss[bt][tt] > th) ? 1 : 0;
  }
  __syncthreads();
  // ---- refine ----
  int a = 0;
  for (int i = 0; i <= tt; ++i) a += sb[bt][i];
  lab[bt][tt] = a;
  __syncthreads();
  if (tt == 0 || lab[bt][tt - 1] != lab[bt][tt]) segst[bt][lab[bt][tt]] = tt;
  __syncthreads();
  const int nb = lab[bt][255];
  const float* Rb = R + (size_t)bt * (256 * 257);
  {
    int c = lab[bt][tt];
    int a1 = segst[bt][c];
    int e1 = (c == nb) ? 255 : (segst[bt][c + 1] - 1);
    const float* Rrow = Rb + (size_t)tt * 257;
    Stm[bt][tt] = Rrow[e1 + 1] - Rrow[a1];
    float cv = 0.f;
    if (c < nb) {
      int a2 = segst[bt][c + 1];
      int e2 = (c + 1 == nb) ? 255 : (segst[bt][c + 2] - 1);
      cv = Rrow[e2 + 1] - Rrow[a2];
    }
    Ctm[bt][tt] = cv;
  }
  __syncthreads();
  for (int c = tt; c <= nb; c += 256) {
    float Dv = 0.f, Sv = 0.f, Cv = 0.f;
    int a1 = segst[bt][c];
    if (a1 >= 0) {
      int e1 = (c == nb) ? 255 : (segst[bt][c + 1] - 1);
      for (int i = a1; i <= e1; ++i) { Dv += degsh[bt][i]; Sv += Stm[bt][i]; Cv += Ctm[bt][i]; }
    }
    Dc[bt][c] = Dv; Scs[bt][c] = Sv; Cr[bt][c] = Cv;
  }
  __syncthreads();
  if (tt == 0) {
    float tot = 0.f;
    for (int i = 0; i < 256; ++i) tot += degsh[bt][i];
    float tote = tot + 1e-10f;
    float Qun = 0.f, Cs = 0.f;
    for (int c = 0; c <= nb; ++c) {
      Qun += Scs[bt][c] - Dc[bt][c] * Dc[bt][c] / tote;
      Cs  += (Dc[bt][c] - Scs[bt][c]) / (fminf(Dc[bt][c], tot - Dc[bt][c]) + 1e-10f);
    }
    shv[bt][0] = tot; shv[bt][1] = tote; shv[bt][2] = Qun; shv[bt][3] = Cs;
    shv[bt][4] = Qun / tote; shv[bt][5] = Cs / (float)(nb + 1);
  }
  __syncthreads();
  int r = sb[bt][tt];
  if (r == 1) {
    float tot = shv[bt][0], tote = shv[bt][1], Qun = shv[bt][2], Cs = shv[bt][3];
    float curQ = shv[bt][4], curC = shv[bt][5];
    int c2 = lab[bt][tt], c1 = c2 - 1;
    if (segst[bt][c1] < 0) {
      float newC0 = Cs / (float)nb;
      if (newC0 < curC) r = 0;
    } else {
      float D1 = Dc[bt][c1], S1 = Scs[bt][c1], D2 = Dc[bt][c2], S2 = Scs[bt][c2];
      float Dm = D1 + D2, Sm = S1 + S2 + 2.0f * Cr[bt][c1];
      float tq1 = S1 - D1 * D1 / tote;
      float tq2 = S2 - D2 * D2 / tote;
      float tqm = Sm - Dm * Dm / tote;
      float newQ = (Qun - tq1 - tq2 + tqm) / tote;
      float tc1 = (D1 - S1) / (fminf(D1, tot - D1) + 1e-10f);
      float tc2 = (D2 - S2) / (fminf(D2, tot - D2) + 1e-10f);
      float tcm = (Dm - Sm) / (fminf(Dm, tot - Dm) + 1e-10f);
      float newC = (Cs - tc1 - tc2 + tcm) / (float)nb;
      if (newQ > curQ || newC < curC) r = 0;
    }
  }
  __syncthreads();
  sb[bt][tt] = r;
  __syncthreads();
  if (tt == 0) {
    int ns = 0, st = 0;
    for (int i = 1; i <= 256; ++i) {
      if (i == 256 || sb[bt][i] == 1) {
        segstL[bt][ns] = st; segcntL[bt][ns] = i - st;
        segst_g[bt * 257 + ns] = st;
        segcnt_g[bt * 257 + ns] = i - st;
        ns++;
        st = i;
      }
    }
    nsL[bt] = ns;
    nseg_g[bt] = ns;
  }
  __syncthreads();
  // ---- slots (threads 0-255) ----
  if (t < 256) {
    int ns0 = nsL[0], total = ns0 + nsL[1];
    int rank = -1;
    for (int r2 = t; r2 < total; r2 += 256) rank = r2;
    int bb = 0, st = 0, ct = 0;
    if (rank >= 0) {
      bb = (rank >= ns0) ? 1 : 0;
      int s = rank - bb * ns0;
      st = segstL[bb][s];
      ct = segcntL[bb][s];
    }
    slotb_g[t] = bb; slotst_g[t] = st; slotcnt_g[t] = ct;
    validsh[t] = (ct > 0 || meml[t] > 0) ? 1 : 0;
  }
  __syncthreads();
  if (t == 0) {
    int k = 0;
    for (int n = 255; n >= 0 && k < 4; --n) if (validsh[n]) cont_g[k++] = n;
    for (int n = 0; n < 256 && k < 4; ++n) if (!validsh[n]) cont_g[k++] = n;
  }
}

// ---------------- K5: scores ----------------
__global__ __launch_bounds__(256) void k_scores(const float* __restrict__ q,
                                                const float* __restrict__ memk,
                                                const int* __restrict__ meml,
                                                const int* __restrict__ slot_b,
                                                const int* __restrict__ slot_start,
                                                const int* __restrict__ slot_cnt,
                                                const float* __restrict__ qm,
                                                float* __restrict__ scores) {
  int wid = blockIdx.x * 4 + (threadIdx.x >> 6);  // 0..511
  int lane = threadIdx.x & 63;
  int b = wid >> 8, n = wid & 255;
  const float* kp = nullptr;
  if (slot_cnt[n] > 0) kp = q + ((size_t)(slot_b[n] * 256 + slot_start[n])) * 512;
  else if (meml[n] > 0) kp = memk + (size_t)n * 512;
  float a = 0.f;
  if (kp) {
    #pragma unroll
    for (int j = 0; j < 8; ++j) a += qm[b * 512 + lane + 64 * j] * kp[lane + 64 * j];
    #pragma unroll
    for (int off = 32; off; off >>= 1) a += __shfl_xor(a, off);
  }
  if (lane == 0) scores[b * 256 + n] = kp ? a : -1000000000.0f;
}

// ---------------- K6: mlp1 with in-block top-8 + gather-by-indirection ----------
__global__ __launch_bounds__(256) void k_mlp1g(const float* __restrict__ q,
                                               const float* __restrict__ memv,
                                               const float* __restrict__ scores,
                                               const int* __restrict__ cont,
                                               const int* __restrict__ slotb,
                                               const int* __restrict__ slotst,
                                               const int* __restrict__ slotcnt,
                                               const float* __restrict__ w1,
                                               const float* __restrict__ b1,
                                               float* __restrict__ h) {
  __shared__ float4 Qs4[512];
  __shared__ float4 Ws4[512];
  __shared__ const float* rowsrc[64];
  __shared__ int topiL[8];
  const int b = blockIdx.x, t = threadIdx.x;
  const int m0 = (b >> 3) * 64, n0 = (b & 7) * 64;
  const int bb = (m0 >= 192) ? 1 : 0;
  // top-8 of this batch's scores (exact serial tie-semantics), wave 0
  if (t < 64) {
    float v[4];
    #pragma unroll
    for (int j = 0; j < 4; ++j) v[j] = scores[bb * 256 + t * 4 + j];
    int chosen = 0;
    for (int k = 0; k < 8; ++k) {
      float best = -3.4e38f; int bi = 0x7fffffff;
      #pragma unroll
      for (int j = 0; j < 4; ++j) {
        if (!(chosen & (1 << j))) {
          float s = v[j]; int n = t * 4 + j;
          if (s > best || (s == best && n < bi)) { best = s; bi = n; }
        }
      }
      #pragma unroll
      for (int off = 32; off; off >>= 1) {
        float ob = __shfl_xor(best, off);
        int oi = __shfl_xor(bi, off);
        if (ob > best || (ob == best && oi < bi)) { best = ob; bi = oi; }
      }
      if ((bi >> 2) == t) chosen |= 1 << (bi & 3);
      if (t == 0) topiL[k] = bi;
    }
  }
  __syncthreads();
  // per-row source pointer (xg row values identical to validated gather)
  if (t < 64) {
    int rr = (m0 + t) - bb * 192;    // 0..191 within batch
    int p = rr & 15;
    int slot = (rr < 128) ? topiL[rr >> 4] : cont[(rr - 128) >> 4];
    int cnt = slotcnt[slot];
    const float* src = nullptr;      // null => zero row
    if (cnt > 0) {
      int ml = cnt < 16 ? cnt : 16;
      if (p < ml) src = q + ((size_t)(slotb[slot] * 256 + slotst[slot] + p)) * 512;
    } else {
      src = memv + ((size_t)slot * 16 + p) * 512;
    }
    rowsrc[t] = src;
  }
  __syncthreads();
  // GEMM with indirect A rows (FMA order identical to validated mlp1)
  const int tn = t & 15, tm = t >> 4;
  const float* Bm = w1 + (size_t)n0 * 512;
  float* Qf = (float*)Qs4;
  float* Wf = (float*)Ws4;
  float acc[4][4] = {};
  #pragma unroll 2
  for (int kc = 0; kc < 512; kc += 32) {
    #pragma unroll
    for (int e = 0; e < 2; ++e) {
      const int idx4 = t + 256 * e;
      const int m = idx4 >> 3;
      const int kg = idx4 & 7;
      const float* rp = rowsrc[m];
      const float4 qa = rp ? *(const float4*)(rp + kc + kg * 4) : make_float4(0.f, 0.f, 0.f, 0.f);
      const float4 wb = *(const float4*)(Bm + (size_t)m * 512 + kc + kg * 4);
      const int fb = ((kg * 4) * 16 + ((m >> 2) ^ kg)) * 4 + (m & 3);
      Qf[fb]       = qa.x; Qf[fb + 64]  = qa.y;
      Qf[fb + 128] = qa.z; Qf[fb + 192] = qa.w;
      Wf[fb]       = wb.x; Wf[fb + 64]  = wb.y;
      Wf[fb + 128] = wb.z; Wf[fb + 192] = wb.w;
    }
    __syncthreads();
    #pragma unroll
    for (int k = 0; k < 32; ++k) {
      const int swz = (k >> 2) & 7;
      const float4 a4 = Qs4[k * 16 + (tm ^ swz)];
      const float4 b4 = Ws4[k * 16 + (tn ^ swz)];
      const float av[4] = {a4.x, a4.y, a4.z, a4.w};
      const float bv[4] = {b4.x, b4.y, b4.z, b4.w};
      #pragma unroll
      for (int i = 0; i < 4; ++i)
        #pragma unroll
        for (int j = 0; j < 4; ++j)
          acc[i][j] += av[i] * bv[j];
    }
    __syncthreads();
  }
  #pragma unroll
  for (int i = 0; i < 4; ++i) {
    int m = m0 + tm * 4 + i;
    #pragma unroll
    for (int j = 0; j < 4; ++j) {
      int n = n0 + tn * 4 + j;
      h[(size_t)m * 512 + n] = fmaxf(acc[i][j] + b1[n], 0.f);
    }
  }
}

// ---------------- K7: mlp2 ----------------
__global__ __launch_bounds__(256) void k_mlp2(const float* __restrict__ h,
                                              const float* __restrict__ w2,
                                              const float* __restrict__ b2,
                                              float* __restrict__ out) {
  __shared__ float4 Qs4[512];
  __shared__ float4 Ws4[512];
  const int b = blockIdx.x;
  int n0 = (b & 7) * 64, m0 = (b >> 3) * 64;
  float acc[4][4] = {};
  gemm64x64_k512(h + (size_t)m0 * 512, w2 + (size_t)n0 * 512, acc, Qs4, Ws4);
  int t = threadIdx.x, tn = t & 15, tm = t >> 4;
  #pragma unroll
  for (int i = 0; i < 4; ++i) {
    int m = m0 + tm * 4 + i;
    int bb = (m >= 192) ? 1 : 0;
    int rr = m - bb * 192;
    int n = n0 + tn * 4;
    float4 v = make_float4(acc[i][0] + b2[n], acc[i][1] + b2[n + 1],
                           acc[i][2] + b2[n + 2], acc[i][3] + b2[n + 3]);
    size_t base = OC1 + ((size_t)(bb * 448 + rr)) * 512 + n;
    *(float4*)&out[base] = v;
    *(float4*)&out[base + NCTX] = v;
  }
}

// ---------------- launch ----------------
extern "C" void kernel_launch(void* const* d_in, const int* in_sizes, int n_in,
                              void* d_out, int out_size, void* d_ws, size_t ws_size,
                              hipStream_t stream) {
  if (ws_size < WS_FLOATS_NEEDED * sizeof(float)) return;

  const float* q     = (const float*)d_in[0];
  const float* key   = (const float*)d_in[1];
  const float* amask = (const float*)d_in[3];
  const int*   tgt   = (const int*)d_in[4];
  const float* bw    = (const float*)d_in[5];
  const float* w1    = (const float*)d_in[6];
  const float* b1    = (const float*)d_in[7];
  const float* w2    = (const float*)d_in[8];
  const float* b2    = (const float*)d_in[9];
  const float* simw  = (const float*)d_in[10];
  const float* simb  = (const float*)d_in[11];
  const float* memk  = (const float*)d_in[12];
  const float* memv  = (const float*)d_in[13];
  const int*   meml  = (const int*)d_in[14];
  float* out = (float*)d_out;

  float* w = (float*)d_ws;
  float* p_partial = w;                      // 256000
  float* p_lse    = p_partial + 256000;      // 512 (unused)
  float* p_sur    = p_lse + 512;             // 512
  float* p_sims   = p_sur + 512;             // 131072
  float* p_R      = p_sims + 131072;         // 131584
  float* p_deg    = p_R + 131584;            // 512
  float* p_qbar   = p_deg + 512;             // 1024
  float* p_qm     = p_qbar + 1024;           // 1024
  float* p_scores = p_qm + 1024;             // 512
  float* p_xg     = p_scores + 512;          // 196608 (unused now)
  float* p_h      = p_xg + 196608;           // 196608
  double* p_pc    = (double*)p_h;            // 8*512 doubles; consumed (K3) before h written (K6)
  int* ip         = (int*)(p_h + 196608);
  int* ip_bnd     = ip;                      // 512 (unused now)
  int* ip_nseg    = ip + 512;                // 2
  int* ip_segst   = ip + 514;                // 514
  int* ip_segcnt  = ip + 1028;               // 514
  int* ip_slotb   = ip + 1542;               // 256
  int* ip_slotst  = ip + 1798;               // 256
  int* ip_slotcnt = ip + 2054;               // 256
  int* ip_topi    = ip + 2310;               // 16 (unused now)
  int* ip_cont    = ip + 2326;               // 4

  k_main<<<K1_NBLK, 256, 0, stream>>>(q, bw, key, amask, p_partial, p_sims, p_qbar, out);
  k_mid<<<400, 256, 0, stream>>>(p_partial, p_sims, p_qbar, simw, simb,
                                 p_pc, p_R, p_deg, p_qm);
  k_sur<<<128, 256, 0, stream>>>(q, bw, tgt, p_pc, p_sur);
  k_bndref<<<1, 512, 0, stream>>>(p_sur, p_R, p_deg, meml,
                                  ip_nseg, ip_segst, ip_segcnt,
                                  ip_slotb, ip_slotst, ip_slotcnt, ip_cont);
  k_scores<<<128, 256, 0, stream>>>(q, memk, meml, ip_slotb, ip_slotst, ip_slotcnt,
                                    p_qm, p_scores);
  k_mlp1g<<<48, 256, 0, stream>>>(q, memv, p_scores, ip_cont,
                                  ip_slotb, ip_slotst, ip_slotcnt, w1, b1, p_h);
  k_mlp2<<<48, 256, 0, stream>>>(p_h, w2, b2, out);
}